// Round 1
// baseline (227.675 us; speedup 1.0000x reference)
//
#include <hip/hip_runtime.h>

#define N_NODES 100000
#define D 64
#define ALPHA 0.2f

// One 64-lane wave per output row. edge_row is sorted, so each wave binary-
// searches its segment [lower_bound(row), lower_bound(row+1)) and accumulates
// vals[e] * h[col[e], lane] over the segment. No atomics, fully deterministic.
__global__ void __launch_bounds__(256) appnp_row_kernel(
    const int* __restrict__ erow,
    const int* __restrict__ ecol,
    const float* __restrict__ evals,
    const float* __restrict__ h,
    const float* __restrict__ h0,
    float* __restrict__ out,
    int n_edges) {
    const int wave_id = (blockIdx.x * blockDim.x + threadIdx.x) >> 6;
    const int lane = threadIdx.x & 63;
    if (wave_id >= N_NODES) return;
    const int row = wave_id;

    // lower_bound(erow, row) — all lanes do the same search; loads are
    // wave-uniform -> single broadcast cacheline per step (~21 steps).
    int lo = 0, hi = n_edges;
    while (lo < hi) {
        int mid = (lo + hi) >> 1;
        if (erow[mid] < row) lo = mid + 1; else hi = mid;
    }
    const int seg_start = lo;
    // lower_bound(erow, row+1), starting from seg_start
    hi = n_edges;
    while (lo < hi) {
        int mid = (lo + hi) >> 1;
        if (erow[mid] < row + 1) lo = mid + 1; else hi = mid;
    }
    const int seg_end = lo;

    float acc = 0.0f;
    int e = seg_start;
    // Unroll x4: four independent gather chains in flight per wave.
    for (; e + 4 <= seg_end; e += 4) {
        const int c0 = ecol[e + 0];
        const int c1 = ecol[e + 1];
        const int c2 = ecol[e + 2];
        const int c3 = ecol[e + 3];
        const float v0 = evals[e + 0];
        const float v1 = evals[e + 1];
        const float v2 = evals[e + 2];
        const float v3 = evals[e + 3];
        const float g0 = h[(size_t)c0 * D + lane];
        const float g1 = h[(size_t)c1 * D + lane];
        const float g2 = h[(size_t)c2 * D + lane];
        const float g3 = h[(size_t)c3 * D + lane];
        acc = fmaf(v0, g0, acc);
        acc = fmaf(v1, g1, acc);
        acc = fmaf(v2, g2, acc);
        acc = fmaf(v3, g3, acc);
    }
    for (; e < seg_end; ++e) {
        const int c = ecol[e];
        const float v = evals[e];
        acc = fmaf(v, h[(size_t)c * D + lane], acc);
    }

    const size_t oidx = (size_t)row * D + lane;
    out[oidx] = (1.0f - ALPHA) * acc + ALPHA * h0[oidx];
}

extern "C" void kernel_launch(void* const* d_in, const int* in_sizes, int n_in,
                              void* d_out, int out_size, void* d_ws, size_t ws_size,
                              hipStream_t stream) {
    const int*   erow  = (const int*)d_in[0];
    const int*   ecol  = (const int*)d_in[1];
    const float* evals = (const float*)d_in[2];
    const float* h     = (const float*)d_in[3];
    const float* h0    = (const float*)d_in[4];
    float* out = (float*)d_out;
    const int n_edges = in_sizes[0];

    // 256 threads = 4 waves = 4 rows per block
    const int rows_per_block = 4;
    const int grid = (N_NODES + rows_per_block - 1) / rows_per_block;
    appnp_row_kernel<<<grid, 256, 0, stream>>>(erow, ecol, evals, h, h0, out, n_edges);
}

// Round 2
// 71.735 us; speedup vs baseline: 3.1738x; 3.1738x over previous
//
#include <hip/hip_runtime.h>

#define N_NODES 100000
#define D 64
#define ALPHA 0.2f

// ---------------------------------------------------------------------------
// Kernel 1: build row_ptr[N+1] from sorted edge_row. Thread e writes
// row_ptr[rr] = e for all rr in (erow[e-1], erow[e]]; thread 0 covers
// [0, erow[0]]; the last thread fills (erow[E-1], N]. Every entry written
// exactly once -> deterministic, no init needed.
// ---------------------------------------------------------------------------
__global__ void __launch_bounds__(256) build_row_ptr(
    const int* __restrict__ erow, int* __restrict__ row_ptr, int n_edges) {
    const int e = blockIdx.x * blockDim.x + threadIdx.x;
    if (e >= n_edges) return;
    const int r = erow[e];
    const int rprev = (e == 0) ? -1 : erow[e - 1];
    for (int rr = rprev + 1; rr <= r; ++rr) row_ptr[rr] = e;
    if (e == n_edges - 1) {
        for (int rr = r + 1; rr <= N_NODES; ++rr) row_ptr[rr] = n_edges;
    }
}

// ---------------------------------------------------------------------------
// Kernel 2: one wave per row. Wave is split into 4 groups of 16 lanes; each
// group handles one edge per step, each lane loads float4 of h[col] (16 B).
// => one gather instruction moves 4 edges (1 KiB). Unroll x2 -> 8 edges in
// flight per wave. Cross-group partials reduced with 2 shfl_xor.
// ---------------------------------------------------------------------------
__global__ void __launch_bounds__(256) appnp_row_kernel(
    const int* __restrict__ row_ptr,
    const int* __restrict__ ecol,
    const float* __restrict__ evals,
    const float* __restrict__ h,
    const float* __restrict__ h0,
    float* __restrict__ out) {
    const int wave_id = (blockIdx.x * blockDim.x + threadIdx.x) >> 6;
    const int lane = threadIdx.x & 63;
    if (wave_id >= N_NODES) return;
    const int row = wave_id;
    const int g = lane >> 4;    // edge-group 0..3
    const int l = lane & 15;    // dim-quad 0..15 (dims 4l..4l+3)

    const int seg_start = row_ptr[row];
    const int seg_end   = row_ptr[row + 1];

    float a0x = 0.f, a0y = 0.f, a0z = 0.f, a0w = 0.f;
    float a1x = 0.f, a1y = 0.f, a1z = 0.f, a1w = 0.f;

    int e = seg_start;
    for (; e + 8 <= seg_end; e += 8) {
        const int   c0 = ecol[e + g];
        const float v0 = evals[e + g];
        const int   c1 = ecol[e + 4 + g];
        const float v1 = evals[e + 4 + g];
        const float4 hv0 = *reinterpret_cast<const float4*>(
            &h[(size_t)c0 * D + l * 4]);
        const float4 hv1 = *reinterpret_cast<const float4*>(
            &h[(size_t)c1 * D + l * 4]);
        a0x = fmaf(v0, hv0.x, a0x); a0y = fmaf(v0, hv0.y, a0y);
        a0z = fmaf(v0, hv0.z, a0z); a0w = fmaf(v0, hv0.w, a0w);
        a1x = fmaf(v1, hv1.x, a1x); a1y = fmaf(v1, hv1.y, a1y);
        a1z = fmaf(v1, hv1.z, a1z); a1w = fmaf(v1, hv1.w, a1w);
    }
    for (; e < seg_end; e += 4) {
        if (e + g < seg_end) {
            const int   c = ecol[e + g];
            const float v = evals[e + g];
            const float4 hv = *reinterpret_cast<const float4*>(
                &h[(size_t)c * D + l * 4]);
            a0x = fmaf(v, hv.x, a0x); a0y = fmaf(v, hv.y, a0y);
            a0z = fmaf(v, hv.z, a0z); a0w = fmaf(v, hv.w, a0w);
        }
    }
    a0x += a1x; a0y += a1y; a0z += a1z; a0w += a1w;

    // Reduce across the 4 groups: lanes {l, l+16, l+32, l+48} hold partials
    // for the same dim-quad.
    a0x += __shfl_xor(a0x, 32); a0y += __shfl_xor(a0y, 32);
    a0z += __shfl_xor(a0z, 32); a0w += __shfl_xor(a0w, 32);
    a0x += __shfl_xor(a0x, 16); a0y += __shfl_xor(a0y, 16);
    a0z += __shfl_xor(a0z, 16); a0w += __shfl_xor(a0w, 16);

    if (lane < 16) {
        const size_t oidx = (size_t)row * D + l * 4;
        const float4 h0v = *reinterpret_cast<const float4*>(&h0[oidx]);
        float4 o;
        o.x = fmaf(1.0f - ALPHA, a0x, ALPHA * h0v.x);
        o.y = fmaf(1.0f - ALPHA, a0y, ALPHA * h0v.y);
        o.z = fmaf(1.0f - ALPHA, a0z, ALPHA * h0v.z);
        o.w = fmaf(1.0f - ALPHA, a0w, ALPHA * h0v.w);
        *reinterpret_cast<float4*>(&out[oidx]) = o;
    }
}

// ---------------------------------------------------------------------------
// Fallback (ws too small): round-1 style binary-search kernel, kept correct.
// ---------------------------------------------------------------------------
__global__ void __launch_bounds__(256) appnp_row_kernel_bsearch(
    const int* __restrict__ erow,
    const int* __restrict__ ecol,
    const float* __restrict__ evals,
    const float* __restrict__ h,
    const float* __restrict__ h0,
    float* __restrict__ out,
    int n_edges) {
    const int wave_id = (blockIdx.x * blockDim.x + threadIdx.x) >> 6;
    const int lane = threadIdx.x & 63;
    if (wave_id >= N_NODES) return;
    const int row = wave_id;
    int lo = 0, hi = n_edges;
    while (lo < hi) { int mid = (lo + hi) >> 1; if (erow[mid] < row) lo = mid + 1; else hi = mid; }
    const int seg_start = lo;
    hi = n_edges;
    while (lo < hi) { int mid = (lo + hi) >> 1; if (erow[mid] < row + 1) lo = mid + 1; else hi = mid; }
    const int seg_end = lo;
    float acc = 0.0f;
    for (int e = seg_start; e < seg_end; ++e)
        acc = fmaf(evals[e], h[(size_t)ecol[e] * D + lane], acc);
    const size_t oidx = (size_t)row * D + lane;
    out[oidx] = (1.0f - ALPHA) * acc + ALPHA * h0[oidx];
}

extern "C" void kernel_launch(void* const* d_in, const int* in_sizes, int n_in,
                              void* d_out, int out_size, void* d_ws, size_t ws_size,
                              hipStream_t stream) {
    const int*   erow  = (const int*)d_in[0];
    const int*   ecol  = (const int*)d_in[1];
    const float* evals = (const float*)d_in[2];
    const float* h     = (const float*)d_in[3];
    const float* h0    = (const float*)d_in[4];
    float* out = (float*)d_out;
    const int n_edges = in_sizes[0];

    const size_t need = (size_t)(N_NODES + 1) * sizeof(int);
    if (ws_size >= need) {
        int* row_ptr = (int*)d_ws;
        build_row_ptr<<<(n_edges + 255) / 256, 256, 0, stream>>>(erow, row_ptr, n_edges);
        const int rows_per_block = 4;  // 256 threads = 4 waves
        const int grid = (N_NODES + rows_per_block - 1) / rows_per_block;
        appnp_row_kernel<<<grid, 256, 0, stream>>>(row_ptr, ecol, evals, h, h0, out);
    } else {
        const int rows_per_block = 4;
        const int grid = (N_NODES + rows_per_block - 1) / rows_per_block;
        appnp_row_kernel_bsearch<<<grid, 256, 0, stream>>>(erow, ecol, evals, h, h0, out, n_edges);
    }
}

// Round 3
// 61.557 us; speedup vs baseline: 3.6986x; 1.1653x over previous
//
#include <hip/hip_runtime.h>

#define N_NODES 100000
#define D 64
#define ALPHA 0.2f

// ---------------------------------------------------------------------------
// Kernel 1: build row_ptr[N+1] from sorted edge_row.
// ---------------------------------------------------------------------------
__global__ void __launch_bounds__(256) build_row_ptr(
    const int* __restrict__ erow, int* __restrict__ row_ptr, int n_edges) {
    const int e = blockIdx.x * blockDim.x + threadIdx.x;
    if (e >= n_edges) return;
    const int r = erow[e];
    const int rprev = (e == 0) ? -1 : erow[e - 1];
    for (int rr = rprev + 1; rr <= r; ++rr) row_ptr[rr] = e;
    if (e == n_edges - 1) {
        for (int rr = r + 1; rr <= N_NODES; ++rr) row_ptr[rr] = n_edges;
    }
}

// ---------------------------------------------------------------------------
// Kernel 2: convert h (fp32, N*64) -> bf16 (RNE), packed 2 per uint.
// Each thread handles 4 floats -> 1 uint2 per grid-stride step.
// ---------------------------------------------------------------------------
__global__ void __launch_bounds__(256) convert_h_bf16(
    const float* __restrict__ h, unsigned int* __restrict__ hb_packed, int n4) {
    // n4 = total_elems / 4
    for (int i = blockIdx.x * blockDim.x + threadIdx.x; i < n4;
         i += gridDim.x * blockDim.x) {
        const float4 f = reinterpret_cast<const float4*>(h)[i];
        union { float f; unsigned int u; } c0, c1, c2, c3;
        c0.f = f.x; c1.f = f.y; c2.f = f.z; c3.f = f.w;
        unsigned int b0 = (c0.u + 0x7FFFu + ((c0.u >> 16) & 1u)) >> 16;
        unsigned int b1 = (c1.u + 0x7FFFu + ((c1.u >> 16) & 1u)) >> 16;
        unsigned int b2 = (c2.u + 0x7FFFu + ((c2.u >> 16) & 1u)) >> 16;
        unsigned int b3 = (c3.u + 0x7FFFu + ((c3.u >> 16) & 1u)) >> 16;
        uint2 o;
        o.x = b0 | (b1 << 16);
        o.y = b2 | (b3 << 16);
        reinterpret_cast<uint2*>(hb_packed)[i] = o;
    }
}

__device__ __forceinline__ float bf_lo(unsigned int u) {
    union { unsigned int u; float f; } c; c.u = u << 16; return c.f;
}
__device__ __forceinline__ float bf_hi(unsigned int u) {
    union { unsigned int u; float f; } c; c.u = u & 0xFFFF0000u; return c.f;
}

// ---------------------------------------------------------------------------
// Kernel 3: one wave per row. 8 edge-groups x 8 lanes; each lane loads 16 B
// (8 bf16 dims) of h[col]. One gather instruction = 8 edges; unroll x2 = 16
// edges in flight. fp32 accumulate; 3-level shfl_xor reduce across groups.
// ---------------------------------------------------------------------------
__global__ void __launch_bounds__(256) appnp_row_bf16(
    const int* __restrict__ row_ptr,
    const int* __restrict__ ecol,
    const float* __restrict__ evals,
    const unsigned short* __restrict__ hb,   // bf16 h, row stride 64
    const float* __restrict__ h0,
    float* __restrict__ out) {
    const int wave_id = (blockIdx.x * blockDim.x + threadIdx.x) >> 6;
    const int lane = threadIdx.x & 63;
    if (wave_id >= N_NODES) return;
    const int row = wave_id;
    const int g = lane >> 3;   // edge slot 0..7
    const int l = lane & 7;    // dim octet: dims 8l..8l+7

    const int seg_start = row_ptr[row];
    const int seg_end   = row_ptr[row + 1];

    float a0 = 0.f, a1 = 0.f, a2 = 0.f, a3 = 0.f,
          a4 = 0.f, a5 = 0.f, a6 = 0.f, a7 = 0.f;
    float b0 = 0.f, b1 = 0.f, b2 = 0.f, b3 = 0.f,
          b4 = 0.f, b5 = 0.f, b6 = 0.f, b7 = 0.f;

    for (int e = seg_start; e < seg_end; e += 16) {
        const int i0 = e + g;
        const int i1 = e + 8 + g;
        const bool m0 = i0 < seg_end;
        const bool m1 = i1 < seg_end;
        const int   c0 = m0 ? ecol[i0] : 0;
        const float v0 = m0 ? evals[i0] : 0.f;
        const int   c1 = m1 ? ecol[i1] : 0;
        const float v1 = m1 ? evals[i1] : 0.f;
        const uint4 p0 = *reinterpret_cast<const uint4*>(
            &hb[(size_t)c0 * D + l * 8]);
        const uint4 p1 = *reinterpret_cast<const uint4*>(
            &hb[(size_t)c1 * D + l * 8]);
        a0 = fmaf(v0, bf_lo(p0.x), a0); a1 = fmaf(v0, bf_hi(p0.x), a1);
        a2 = fmaf(v0, bf_lo(p0.y), a2); a3 = fmaf(v0, bf_hi(p0.y), a3);
        a4 = fmaf(v0, bf_lo(p0.z), a4); a5 = fmaf(v0, bf_hi(p0.z), a5);
        a6 = fmaf(v0, bf_lo(p0.w), a6); a7 = fmaf(v0, bf_hi(p0.w), a7);
        b0 = fmaf(v1, bf_lo(p1.x), b0); b1 = fmaf(v1, bf_hi(p1.x), b1);
        b2 = fmaf(v1, bf_lo(p1.y), b2); b3 = fmaf(v1, bf_hi(p1.y), b3);
        b4 = fmaf(v1, bf_lo(p1.z), b4); b5 = fmaf(v1, bf_hi(p1.z), b5);
        b6 = fmaf(v1, bf_lo(p1.w), b6); b7 = fmaf(v1, bf_hi(p1.w), b7);
    }
    a0 += b0; a1 += b1; a2 += b2; a3 += b3;
    a4 += b4; a5 += b5; a6 += b6; a7 += b7;

    // Reduce across the 8 groups (lane bits 3..5).
    #define RED(mask) \
        a0 += __shfl_xor(a0, mask); a1 += __shfl_xor(a1, mask); \
        a2 += __shfl_xor(a2, mask); a3 += __shfl_xor(a3, mask); \
        a4 += __shfl_xor(a4, mask); a5 += __shfl_xor(a5, mask); \
        a6 += __shfl_xor(a6, mask); a7 += __shfl_xor(a7, mask);
    RED(8) RED(16) RED(32)
    #undef RED

    if (g == 0) {
        const size_t oidx = (size_t)row * D + l * 8;
        const float4 h0a = *reinterpret_cast<const float4*>(&h0[oidx]);
        const float4 h0b = *reinterpret_cast<const float4*>(&h0[oidx + 4]);
        float4 oA, oB;
        oA.x = fmaf(1.0f - ALPHA, a0, ALPHA * h0a.x);
        oA.y = fmaf(1.0f - ALPHA, a1, ALPHA * h0a.y);
        oA.z = fmaf(1.0f - ALPHA, a2, ALPHA * h0a.z);
        oA.w = fmaf(1.0f - ALPHA, a3, ALPHA * h0a.w);
        oB.x = fmaf(1.0f - ALPHA, a4, ALPHA * h0b.x);
        oB.y = fmaf(1.0f - ALPHA, a5, ALPHA * h0b.y);
        oB.z = fmaf(1.0f - ALPHA, a6, ALPHA * h0b.z);
        oB.w = fmaf(1.0f - ALPHA, a7, ALPHA * h0b.w);
        *reinterpret_cast<float4*>(&out[oidx])     = oA;
        *reinterpret_cast<float4*>(&out[oidx + 4]) = oB;
    }
}

// ---------------------------------------------------------------------------
// Fallback: round-2 fp32 kernel (row_ptr version).
// ---------------------------------------------------------------------------
__global__ void __launch_bounds__(256) appnp_row_fp32(
    const int* __restrict__ row_ptr,
    const int* __restrict__ ecol,
    const float* __restrict__ evals,
    const float* __restrict__ h,
    const float* __restrict__ h0,
    float* __restrict__ out) {
    const int wave_id = (blockIdx.x * blockDim.x + threadIdx.x) >> 6;
    const int lane = threadIdx.x & 63;
    if (wave_id >= N_NODES) return;
    const int row = wave_id;
    const int seg_start = row_ptr[row];
    const int seg_end   = row_ptr[row + 1];
    float acc = 0.0f;
    for (int e = seg_start; e < seg_end; ++e)
        acc = fmaf(evals[e], h[(size_t)ecol[e] * D + lane], acc);
    const size_t oidx = (size_t)row * D + lane;
    out[oidx] = (1.0f - ALPHA) * acc + ALPHA * h0[oidx];
}

// Last-resort fallback: binary search, no workspace at all.
__global__ void __launch_bounds__(256) appnp_row_bsearch(
    const int* __restrict__ erow,
    const int* __restrict__ ecol,
    const float* __restrict__ evals,
    const float* __restrict__ h,
    const float* __restrict__ h0,
    float* __restrict__ out,
    int n_edges) {
    const int wave_id = (blockIdx.x * blockDim.x + threadIdx.x) >> 6;
    const int lane = threadIdx.x & 63;
    if (wave_id >= N_NODES) return;
    const int row = wave_id;
    int lo = 0, hi = n_edges;
    while (lo < hi) { int mid = (lo + hi) >> 1; if (erow[mid] < row) lo = mid + 1; else hi = mid; }
    const int seg_start = lo;
    hi = n_edges;
    while (lo < hi) { int mid = (lo + hi) >> 1; if (erow[mid] < row + 1) lo = mid + 1; else hi = mid; }
    const int seg_end = lo;
    float acc = 0.0f;
    for (int e = seg_start; e < seg_end; ++e)
        acc = fmaf(evals[e], h[(size_t)ecol[e] * D + lane], acc);
    const size_t oidx = (size_t)row * D + lane;
    out[oidx] = (1.0f - ALPHA) * acc + ALPHA * h0[oidx];
}

extern "C" void kernel_launch(void* const* d_in, const int* in_sizes, int n_in,
                              void* d_out, int out_size, void* d_ws, size_t ws_size,
                              hipStream_t stream) {
    const int*   erow  = (const int*)d_in[0];
    const int*   ecol  = (const int*)d_in[1];
    const float* evals = (const float*)d_in[2];
    const float* h     = (const float*)d_in[3];
    const float* h0    = (const float*)d_in[4];
    float* out = (float*)d_out;
    const int n_edges = in_sizes[0];

    const size_t rowptr_bytes = (size_t)(N_NODES + 1) * sizeof(int);
    const size_t rowptr_pad   = (rowptr_bytes + 255) & ~(size_t)255;
    const size_t hb_bytes     = (size_t)N_NODES * D * sizeof(unsigned short);
    const int rows_per_block  = 4;   // 256 threads = 4 waves
    const int grid = (N_NODES + rows_per_block - 1) / rows_per_block;

    if (ws_size >= rowptr_pad + hb_bytes) {
        int* row_ptr = (int*)d_ws;
        unsigned int* hb_packed = (unsigned int*)((char*)d_ws + rowptr_pad);
        build_row_ptr<<<(n_edges + 255) / 256, 256, 0, stream>>>(
            erow, row_ptr, n_edges);
        const int n4 = N_NODES * D / 4;
        convert_h_bf16<<<2048, 256, 0, stream>>>(h, hb_packed, n4);
        appnp_row_bf16<<<grid, 256, 0, stream>>>(
            row_ptr, ecol, evals, (const unsigned short*)hb_packed, h0, out);
    } else if (ws_size >= rowptr_bytes) {
        int* row_ptr = (int*)d_ws;
        build_row_ptr<<<(n_edges + 255) / 256, 256, 0, stream>>>(
            erow, row_ptr, n_edges);
        appnp_row_fp32<<<grid, 256, 0, stream>>>(
            row_ptr, ecol, evals, h, h0, out);
    } else {
        appnp_row_bsearch<<<grid, 256, 0, stream>>>(
            erow, ecol, evals, h, h0, out, n_edges);
    }
}